// Round 14
// baseline (43.879 us; speedup 1.0000x reference)
//
#include <hip/hip_runtime.h>
#include <cstdint>

#define IN_F 4096
#define OUT_F 11008
#define Q_OUT 5504
#define GROUP 128
#define BATCH 32

#define KBS 8            // k-splits
#define GPB 4            // quant groups per K=512 slice
#define NCH 8            // 64-k chunks per K=512 slice
#define BST 18           // fallback b_lds stride

typedef int   i32x4 __attribute__((ext_vector_type(4)));
typedef float f32x4 __attribute__((ext_vector_type(4)));

// ---------------------------------------------------------------------------
// Prep: blocks 0..31 quantize x rows to i8 (A-frag order) + Sx + delta;
//       blocks 32..117 init out = bias (gemm atomics accumulate).
// ---------------------------------------------------------------------------
__global__ __launch_bounds__(256)
void prep_kernel(const float* __restrict__ x,
                 const float* __restrict__ bias,
                 uint4* __restrict__ xq,
                 int*   __restrict__ Sx,
                 float* __restrict__ delta,
                 float* __restrict__ out)
{
    const int t = threadIdx.x;
    if (blockIdx.x >= 32) {
        const int base = (blockIdx.x - 32) * 4096 + t * 16;
        #pragma unroll
        for (int i = 0; i < 4; ++i)
            *reinterpret_cast<float4*>(out + base + i * 4) =
                *reinterpret_cast<const float4*>(bias + ((base + i * 4) % OUT_F));
        return;
    }
    const int m = blockIdx.x;
    const float* xr = x + (size_t)m * IN_F + t * 16;
    float4 v[4];
    #pragma unroll
    for (int i = 0; i < 4; ++i) v[i] = reinterpret_cast<const float4*>(xr)[i];

    float lm = 0.f;
    #pragma unroll
    for (int i = 0; i < 4; ++i)
        lm = fmaxf(lm, fmaxf(fmaxf(fabsf(v[i].x), fabsf(v[i].y)),
                             fmaxf(fabsf(v[i].z), fabsf(v[i].w))));
    #pragma unroll
    for (int d = 32; d; d >>= 1) lm = fmaxf(lm, __shfl_xor(lm, d));
    __shared__ float wred[4];
    if ((t & 63) == 0) wred[t >> 6] = lm;
    __syncthreads();
    const float mx  = fmaxf(fmaxf(wred[0], wred[1]), fmaxf(wred[2], wred[3]));
    const float inv = mx > 0.f ? 127.0f / mx : 0.f;

    int q[16];
    #pragma unroll
    for (int i = 0; i < 4; ++i) {
        q[i * 4 + 0] = __float2int_rn(v[i].x * inv);
        q[i * 4 + 1] = __float2int_rn(v[i].y * inv);
        q[i * 4 + 2] = __float2int_rn(v[i].z * inv);
        q[i * 4 + 3] = __float2int_rn(v[i].w * inv);
    }
    uint4 w;
    uint* wp = reinterpret_cast<uint*>(&w);
    #pragma unroll
    for (int i = 0; i < 4; ++i)
        wp[i] = (q[i*4] & 255) | ((q[i*4+1] & 255) << 8) |
                ((q[i*4+2] & 255) << 16) | ((q[i*4+3] & 255) << 24);
    xq[(t >> 2) * 128 + (m >> 4) * 64 + (t & 3) * 16 + (m & 15)] = w;

    int psum = 0;
    #pragma unroll
    for (int i = 0; i < 16; ++i) psum += q[i];
    #pragma unroll
    for (int d = 4; d; d >>= 1) psum += __shfl_down(psum, d, 8);
    if ((t & 7) == 0) Sx[(t >> 3) * 32 + m] = psum;
    if (t == 0) delta[m] = mx * (1.0f / 127.0f);
}

// ---------------------------------------------------------------------------
// Repack: pure latency-tolerant stream. qweight ints carry 1 payload byte;
// emit dense B-fragment-ordered bytes:
//   qb byte[ ((W*8+kb)*8+c)*512 + p*64 + kg*16 + j ] =
//       lowbyte( qw[ kb*512 + c*64 + kg*16 + j ][ 8W + p ] )
// Thread (lane,rq) @ block (pcb,kb): pc = pcb*64+lane, kg = rq; per chunk c
// issues 16 independent 4-B loads (64-lane instr = 256-B coalesced run),
// packs 16 bytes, writes ONE dwordx4. 90 MB read at streaming rate.
// ---------------------------------------------------------------------------
__global__ __launch_bounds__(256)
void repack_kernel(const int* __restrict__ qw, uint4* __restrict__ qb)
{
    const int t    = threadIdx.x;
    const int lane = t & 63;
    const int rq   = t >> 6;              // kg
    const int pc   = blockIdx.x * 64 + lane;
    const int kb   = blockIdx.y;
    const int W    = pc >> 3;
    const int p    = pc & 7;

    #pragma unroll 1
    for (int c = 0; c < 8; ++c) {
        const int krow = kb * 512 + c * 64 + rq * 16;
        const int* src = qw + (size_t)krow * Q_OUT + pc;
        uint b[16];
        #pragma unroll
        for (int i = 0; i < 16; ++i) b[i] = (uint)src[(size_t)i * Q_OUT] & 255u;
        uint4 w;
        w.x = b[0]  | (b[1]  << 8) | (b[2]  << 16) | (b[3]  << 24);
        w.y = b[4]  | (b[5]  << 8) | (b[6]  << 16) | (b[7]  << 24);
        w.z = b[8]  | (b[9]  << 8) | (b[10] << 16) | (b[11] << 24);
        w.w = b[12] | (b[13] << 8) | (b[14] << 16) | (b[15] << 24);
        // uint4 slot index: ((W*8+kb)*8+c)*32 + p*4 + rq
        qb[((size_t)(W * 8 + kb) * 8 + c) * 32 + p * 4 + rq] = w;
    }
}

// ---------------------------------------------------------------------------
// LDS-free, barrier-free GEMM. Wave (wid of block.x, kb=block.y) owns
// W = bx*4+wid: cols 16W..16W+15, m 0..31, K = kb*512..+511 (8 chunks).
// Per chunk: B-frag = ONE dwordx4 from qb (L2/L3-hot, dense), A = 2 dwordx4
// from xq (L2-hot), 4 nibble-extract VALU, 2 MFMA. 4-deep rolling prefetch,
// refilled AFTER consumption (r7 discipline). No LDS -> no duty-cycle hole.
// ---------------------------------------------------------------------------
__global__ __launch_bounds__(256, 4)
void int4_gemm_qb(const uint4* __restrict__ xq,
                  const uint4* __restrict__ qb,
                  const float* __restrict__ scales,
                  const int*   __restrict__ qz,
                  const int*   __restrict__ Sx,
                  const float* __restrict__ delta,
                  float*       __restrict__ out)
{
    const int tid  = threadIdx.x;
    const int lane = tid & 63;
    const int wid  = tid >> 6;
    const int W    = blockIdx.x * 4 + wid;   // 0..687
    const int kb   = blockIdx.y;             // 0..7
    const int g0   = kb * GPB;

    const int cl  = lane & 15;
    const int kg  = lane >> 4;
    const int n   = W * 16 + cl;
    const int p   = cl >> 1;
    const int shn = (cl & 1) * 4;

    int   zv[GPB];
    float sv[GPB];
    #pragma unroll
    for (int g = 0; g < GPB; ++g) {
        sv[g] = scales[(size_t)(g0 + g) * OUT_F + n];
        zv[g] = (qz[(size_t)(g0 + g) * Q_OUT + (n >> 1)] >> shn) & 15;
    }

    const size_t btile = ((size_t)(W * 8 + kb) * 8) * 32 + p * 4 + kg;  // + c*32
    const size_t atile = (size_t)kb * 1024;                             // + c*128

    uint4 B[4];
    uint4 A[4][2];
    #pragma unroll
    for (int c = 0; c < 4; ++c) {
        B[c]    = qb[btile + (size_t)c * 32];
        A[c][0] = xq[atile + (size_t)c * 128 + lane];
        A[c][1] = xq[atile + (size_t)c * 128 + 64 + lane];
    }

    i32x4 acc_i[2] = {};
    f32x4 accf[2]  = {};
    int4  sx0v = {}, sx1v = {};

    #pragma unroll
    for (int c = 0; c < NCH; ++c) {
        const int s  = c & 3;
        const int gl = c >> 1;
        if ((c & 1) == 0) {
            sx0v = *reinterpret_cast<const int4*>(Sx + (g0 + gl) * 32 + kg * 4);
            sx1v = *reinterpret_cast<const int4*>(Sx + (g0 + gl) * 32 + 16 + kg * 4);
        }

        uint4 bq = B[s];
        i32x4 bv;
        bv[0] = (int)((bq.x >> shn) & 0x0F0F0F0Fu);
        bv[1] = (int)((bq.y >> shn) & 0x0F0F0F0Fu);
        bv[2] = (int)((bq.z >> shn) & 0x0F0F0F0Fu);
        bv[3] = (int)((bq.w >> shn) & 0x0F0F0F0Fu);

        acc_i[0] = __builtin_amdgcn_mfma_i32_16x16x64_i8(
            __builtin_bit_cast(i32x4, A[s][0]), bv, acc_i[0], 0, 0, 0);
        acc_i[1] = __builtin_amdgcn_mfma_i32_16x16x64_i8(
            __builtin_bit_cast(i32x4, A[s][1]), bv, acc_i[1], 0, 0, 0);

        // refill set AFTER consumption (same registers; r7 lesson)
        if (c + 4 < NCH) {
            B[s]    = qb[btile + (size_t)(c + 4) * 32];
            A[s][0] = xq[atile + (size_t)(c + 4) * 128 + lane];
            A[s][1] = xq[atile + (size_t)(c + 4) * 128 + 64 + lane];
        }

        if (c & 1) {
            const int   zz = zv[gl];
            const float ss = sv[gl];
            int sxa[8] = { sx0v.x, sx0v.y, sx0v.z, sx0v.w,
                           sx1v.x, sx1v.y, sx1v.z, sx1v.w };
            #pragma unroll
            for (int f = 0; f < 2; ++f)
                #pragma unroll
                for (int r = 0; r < 4; ++r) {
                    int tt = acc_i[f][r] - zz * sxa[f * 4 + r];
                    accf[f][r] = fmaf(ss, (float)tt, accf[f][r]);
                }
            acc_i[0] = i32x4{0, 0, 0, 0};
            acc_i[1] = i32x4{0, 0, 0, 0};
        }
    }

    float4 dl0 = *reinterpret_cast<const float4*>(delta + kg * 4);
    float4 dl1 = *reinterpret_cast<const float4*>(delta + 16 + kg * 4);
    const float dla[8] = { dl0.x, dl0.y, dl0.z, dl0.w, dl1.x, dl1.y, dl1.z, dl1.w };
    #pragma unroll
    for (int f = 0; f < 2; ++f)
        #pragma unroll
        for (int r = 0; r < 4; ++r) {
            const int m = f * 16 + kg * 4 + r;
            unsafeAtomicAdd(out + (size_t)m * OUT_F + n, dla[f * 4 + r] * accf[f][r]);
        }
}

// ---------------------------------------------------------------------------
// Fallback GEMM (r5 verbatim, 28.4 us) if ws_size can't hold qb.
// ---------------------------------------------------------------------------
__global__ __launch_bounds__(256, 4)
void int4_gemm_fb(const uint4* __restrict__ xq,
                  const int*   __restrict__ qw,
                  const float* __restrict__ scales,
                  const int*   __restrict__ qz,
                  const int*   __restrict__ Sx,
                  const float* __restrict__ delta,
                  float*       __restrict__ out)
{
    const int tid  = threadIdx.x;
    const int lane = tid & 63;
    const int wid  = tid >> 6;
    const int nb   = blockIdx.x;
    const int kb   = blockIdx.y;
    const int g0   = kb * GPB;
    const int k0b  = g0 * GROUP;

    __shared__ uint4 a_lds[1024];
    __shared__ int   b_lds[2][64 * BST];

    const int cl  = lane & 15;
    const int kg  = lane >> 4;
    const int n   = nb * 64 + wid * 16 + cl;
    const int shn = (cl & 1) * 4;

    #pragma unroll
    for (int r = 0; r < 4; ++r) {
        const uint4* gp = xq + (size_t)kb * 1024 + r * 256 + tid;
        __builtin_amdgcn_global_load_lds(
            (const __attribute__((address_space(1))) uint32_t*)gp,
            (__attribute__((address_space(3))) uint32_t*)&a_lds[r * 256 + wid * 64],
            16, 0, 0);
    }

    int   zv[GPB];
    float sv[GPB];
    #pragma unroll
    for (int g = 0; g < GPB; ++g) {
        sv[g] = scales[(size_t)(g0 + g) * OUT_F + n];
        zv[g] = (qz[(size_t)(g0 + g) * Q_OUT + (n >> 1)] >> shn) & 15;
    }

    const int a16 = tid & 15;
    const int rk  = tid >> 4;

    uint2 d[2][4];
    i32x4 acc_i[2] = {};
    f32x4 accf[2]  = {};
    int4  sx0v = {}, sx1v = {};

    auto LOADB = [&](int c, int set) {
        const int kr = k0b + c * 64 + 4 * rk;
        #pragma unroll
        for (int i = 0; i < 4; ++i)
            d[set][i] = *reinterpret_cast<const uint2*>(
                qw + (size_t)(kr + i) * Q_OUT + nb * 32 + 2 * a16);
    };
    auto WLDS = [&](int buf, int set) {
        #pragma unroll
        for (int j = 0; j < 2; ++j) {
            uint b0 = (j ? d[set][0].y : d[set][0].x) & 255u;
            uint b1 = (j ? d[set][1].y : d[set][1].x) & 255u;
            uint b2 = (j ? d[set][2].y : d[set][2].x) & 255u;
            uint b3 = (j ? d[set][3].y : d[set][3].x) & 255u;
            uint p  = b0 | (b1 << 8) | (b2 << 16) | (b3 << 24);
            const int nloc = 4 * a16 + 2 * j;
            b_lds[buf][(nloc + 0) * BST + rk] = (int)(p & 0x0F0F0F0Fu);
            b_lds[buf][(nloc + 1) * BST + rk] = (int)((p >> 4) & 0x0F0F0F0Fu);
        }
    };

    LOADB(0, 0);
    LOADB(1, 1);
    WLDS(0, 0);
    asm volatile("s_waitcnt vmcnt(0) lgkmcnt(0)" ::: "memory");
    __builtin_amdgcn_s_barrier();
    asm volatile("" ::: "memory");

    #pragma unroll
    for (int c = 0; c < NCH; ++c) {
        const int cur = c & 1;
        const int gl  = c >> 1;
        if (c + 2 < NCH) LOADB(c + 2, cur);
        if ((c & 1) == 0) {
            sx0v = *reinterpret_cast<const int4*>(Sx + (g0 + gl) * 32 + kg * 4);
            sx1v = *reinterpret_cast<const int4*>(Sx + (g0 + gl) * 32 + 16 + kg * 4);
        }

        const int* bp = &b_lds[cur][(wid * 16 + cl) * BST + 4 * kg];
        int2 qa = *reinterpret_cast<const int2*>(bp);
        int2 qb2 = *reinterpret_cast<const int2*>(bp + 2);
        i32x4 bv; bv[0] = qa.x; bv[1] = qa.y; bv[2] = qb2.x; bv[3] = qb2.y;

        uint4 a0 = a_lds[(c * 2 + 0) * 64 + lane];
        uint4 a1 = a_lds[(c * 2 + 1) * 64 + lane];
        acc_i[0] = __builtin_amdgcn_mfma_i32_16x16x64_i8(
            __builtin_bit_cast(i32x4, a0), bv, acc_i[0], 0, 0, 0);
        acc_i[1] = __builtin_amdgcn_mfma_i32_16x16x64_i8(
            __builtin_bit_cast(i32x4, a1), bv, acc_i[1], 0, 0, 0);

        if (c & 1) {
            const int   zz = zv[gl];
            const float ss = sv[gl];
            int sxa[8] = { sx0v.x, sx0v.y, sx0v.z, sx0v.w,
                           sx1v.x, sx1v.y, sx1v.z, sx1v.w };
            #pragma unroll
            for (int f = 0; f < 2; ++f)
                #pragma unroll
                for (int r = 0; r < 4; ++r) {
                    int tt = acc_i[f][r] - zz * sxa[f * 4 + r];
                    accf[f][r] = fmaf(ss, (float)tt, accf[f][r]);
                }
            acc_i[0] = i32x4{0, 0, 0, 0};
            acc_i[1] = i32x4{0, 0, 0, 0};
        }

        if (c + 1 < NCH) {
            WLDS(cur ^ 1, cur ^ 1);
            asm volatile("s_waitcnt lgkmcnt(0)" ::: "memory");
            __builtin_amdgcn_s_barrier();
            asm volatile("" ::: "memory");
        }
    }

    float4 dl0 = *reinterpret_cast<const float4*>(delta + kg * 4);
    float4 dl1 = *reinterpret_cast<const float4*>(delta + 16 + kg * 4);
    const float dla[8] = { dl0.x, dl0.y, dl0.z, dl0.w, dl1.x, dl1.y, dl1.z, dl1.w };
    #pragma unroll
    for (int f = 0; f < 2; ++f)
        #pragma unroll
        for (int r = 0; r < 4; ++r) {
            const int m = f * 16 + kg * 4 + r;
            unsafeAtomicAdd(out + (size_t)m * OUT_F + n, dla[f * 4 + r] * accf[f][r]);
        }
}

extern "C" void kernel_launch(void* const* d_in, const int* in_sizes, int n_in,
                              void* d_out, int out_size, void* d_ws, size_t ws_size,
                              hipStream_t stream)
{
    const float* inp    = (const float*)d_in[0];
    const int*   qw     = (const int*)d_in[1];
    const float* scales = (const float*)d_in[2];
    const int*   qz     = (const int*)d_in[3];
    const float* bias   = (const float*)d_in[4];
    float*       out    = (float*)d_out;

    uint4* xq    = (uint4*)d_ws;                          // 128 KB
    int*   Sx    = (int*)((char*)d_ws + 131072);          // 4 KB
    float* delta = (float*)((char*)d_ws + 131072 + 4096); // 128 B

    const size_t QB_OFF   = (size_t)1 << 20;              // 1 MB
    const size_t QB_BYTES = (size_t)688 * 8 * 8 * 512;    // 22,544,384

    prep_kernel<<<118, 256, 0, stream>>>(inp, bias, xq, Sx, delta, out);

    if (ws_size >= QB_OFF + QB_BYTES) {
        uint4* qb = (uint4*)((char*)d_ws + QB_OFF);
        repack_kernel<<<dim3(Q_OUT / 64, KBS), 256, 0, stream>>>(qw, qb);
        int4_gemm_qb<<<dim3(688 / 4, KBS), 256, 0, stream>>>(
            xq, qb, scales, qz, Sx, delta, out);
    } else {
        int4_gemm_fb<<<dim3(OUT_F / 64, KBS), 256, 0, stream>>>(
            xq, qw, scales, qz, Sx, delta, out);
    }
}

// Round 15
// 29.605 us; speedup vs baseline: 1.4822x; 1.4822x over previous
//
#include <hip/hip_runtime.h>
#include <cstdint>

#define IN_F 4096
#define OUT_F 11008
#define Q_OUT 5504
#define GROUP 128
#define BATCH 32

#define KBS 8            // k-splits; == 8 XCDs (kb = bid & 7 -> XCD id)
#define GPB 4            // quant groups per block
#define NCH 8            // 64-k chunks per block (K=512)
#define BN 64            // output cols per block
#define BST 18           // b_lds dword stride per n-row: 16 data + 2 pad

typedef int   i32x4 __attribute__((ext_vector_type(4)));
typedef float f32x4 __attribute__((ext_vector_type(4)));

// ---------------------------------------------------------------------------
// Prep kernel, two roles by blockIdx:
//  blocks 0..31: row m: maxabs -> delta[m]; quantize x to i8 in MFMA A-frag
//    order; per-group row sums Sx[g][m] (i32, exact).
//  blocks 32..117: out[m][n] = bias[n]  (16 floats/thread; gemm atomics add)
// ---------------------------------------------------------------------------
__global__ __launch_bounds__(256)
void prep_kernel(const float* __restrict__ x,
                 const float* __restrict__ bias,
                 uint4* __restrict__ xq,     // 8192 slots of 16 i8
                 int*   __restrict__ Sx,     // [32 g][32 m]
                 float* __restrict__ delta,  // [32]
                 float* __restrict__ out)
{
    const int t = threadIdx.x;
    if (blockIdx.x >= 32) {
        const int base = (blockIdx.x - 32) * 4096 + t * 16;
        #pragma unroll
        for (int i = 0; i < 4; ++i)
            *reinterpret_cast<float4*>(out + base + i * 4) =
                *reinterpret_cast<const float4*>(bias + ((base + i * 4) % OUT_F));
        return;
    }
    const int m = blockIdx.x;
    const float* xr = x + (size_t)m * IN_F + t * 16;  // thread owns k=16t..16t+15
    float4 v[4];
    #pragma unroll
    for (int i = 0; i < 4; ++i) v[i] = reinterpret_cast<const float4*>(xr)[i];

    float lm = 0.f;
    #pragma unroll
    for (int i = 0; i < 4; ++i) {
        lm = fmaxf(lm, fmaxf(fmaxf(fabsf(v[i].x), fabsf(v[i].y)),
                             fmaxf(fabsf(v[i].z), fabsf(v[i].w))));
    }
    #pragma unroll
    for (int d = 32; d; d >>= 1) lm = fmaxf(lm, __shfl_xor(lm, d));
    __shared__ float wred[4];
    if ((t & 63) == 0) wred[t >> 6] = lm;
    __syncthreads();
    const float mx  = fmaxf(fmaxf(wred[0], wred[1]), fmaxf(wred[2], wred[3]));
    const float inv = mx > 0.f ? 127.0f / mx : 0.f;

    int q[16];
    #pragma unroll
    for (int i = 0; i < 4; ++i) {
        q[i * 4 + 0] = __float2int_rn(v[i].x * inv);
        q[i * 4 + 1] = __float2int_rn(v[i].y * inv);
        q[i * 4 + 2] = __float2int_rn(v[i].z * inv);
        q[i * 4 + 3] = __float2int_rn(v[i].w * inv);
    }
    uint4 w;
    uint* wp = reinterpret_cast<uint*>(&w);
    #pragma unroll
    for (int i = 0; i < 4; ++i)
        wp[i] = (q[i*4] & 255) | ((q[i*4+1] & 255) << 8) |
                ((q[i*4+2] & 255) << 16) | ((q[i*4+3] & 255) << 24);
    // slot = S*128 + f*64 + kg*16 + (m&15);  S=t>>2, kg=t&3, f=m>>4
    xq[(t >> 2) * 128 + (m >> 4) * 64 + (t & 3) * 16 + (m & 15)] = w;

    int psum = 0;
    #pragma unroll
    for (int i = 0; i < 16; ++i) psum += q[i];
    #pragma unroll
    for (int d = 4; d; d >>= 1) psum += __shfl_down(psum, d, 8);
    if ((t & 7) == 0) Sx[(t >> 3) * 32 + m] = psum;   // g = t>>3
    if (t == 0) delta[m] = mx * (1.0f / 127.0f);
}

// ---------------------------------------------------------------------------
// GEMM == r5 (28.4 us, best) byte-for-byte EXCEPT the grid is 1-D and
// decoded kb = bid & 7, nb = bid >> 3. Default dispatch assigns block i ->
// XCD i%8 [m09], so ALL blocks of one k-slab (kb) land on ONE XCD: each XCD
// streams a private contiguous 11 MB slab of qweight (rows kb*512..+512)
// instead of all 8 XCDs fragmenting the full 90 MB -> DRAM page/channel
// locality + 8x less L3->L2 footprint per XCD. Tests the cross-block
// locality family that r8/r10 (within-instruction runs) never touched.
// ---------------------------------------------------------------------------
__global__ __launch_bounds__(256, 4)
void int4_gemm_i8(const uint4* __restrict__ xq,
                  const int*   __restrict__ qw,
                  const float* __restrict__ scales,
                  const int*   __restrict__ qz,
                  const int*   __restrict__ Sx,
                  const float* __restrict__ delta,
                  float*       __restrict__ out)
{
    const int tid  = threadIdx.x;
    const int lane = tid & 63;
    const int wid  = tid >> 6;
    const int kb   = blockIdx.x & 7;      // XCD id == k-slab id
    const int nb   = blockIdx.x >> 3;     // 0..171
    const int g0   = kb * GPB;
    const int k0b  = g0 * GROUP;

    __shared__ uint4 a_lds[1024];         // 16 KB, read-only after prologue
    __shared__ int   b_lds[2][64 * BST];  // 2 x 4.5 KB

    const int cl  = lane & 15;
    const int kg  = lane >> 4;
    const int n   = nb * BN + wid * 16 + cl;
    const int shn = (cl & 1) * 4;

    // ---- A stage: this kb's 1024 contiguous uint4 slots -> LDS, linear ----
    #pragma unroll
    for (int r = 0; r < 4; ++r) {
        const uint4* gp = xq + (size_t)kb * 1024 + r * 256 + tid;
        __builtin_amdgcn_global_load_lds(
            (const __attribute__((address_space(1))) uint32_t*)gp,
            (__attribute__((address_space(3))) uint32_t*)&a_lds[r * 256 + wid * 64],
            16, 0, 0);
    }

    // per-group constants
    int   zv[GPB];
    float sv[GPB];
    #pragma unroll
    for (int g = 0; g < GPB; ++g) {
        sv[g] = scales[(size_t)(g0 + g) * OUT_F + n];
        zv[g] = (qz[(size_t)(g0 + g) * Q_OUT + (n >> 1)] >> shn) & 15;
    }

    // B staging: thread (a16 = words 2a16,2a16+1; rk = rows 4rk..4rk+3)
    const int a16 = tid & 15;
    const int rk  = tid >> 4;

    uint2 d[2][4];                        // [set][row]
    i32x4 acc_i[2] = {};
    f32x4 accf[2]  = {};
    int4  sx0v = {}, sx1v = {};

    auto LOADB = [&](int c, int set) {
        const int kr = k0b + c * 64 + 4 * rk;
        #pragma unroll
        for (int i = 0; i < 4; ++i)
            d[set][i] = *reinterpret_cast<const uint2*>(
                qw + (size_t)(kr + i) * Q_OUT + nb * 32 + 2 * a16);
    };
    auto WLDS = [&](int buf, int set) {
        #pragma unroll
        for (int j = 0; j < 2; ++j) {
            // k-major dword: low bytes of 4 consecutive k-rows, word 2a16+j
            uint b0 = (j ? d[set][0].y : d[set][0].x) & 255u;
            uint b1 = (j ? d[set][1].y : d[set][1].x) & 255u;
            uint b2 = (j ? d[set][2].y : d[set][2].x) & 255u;
            uint b3 = (j ? d[set][3].y : d[set][3].x) & 255u;
            uint p  = b0 | (b1 << 8) | (b2 << 16) | (b3 << 24);
            const int nloc = 4 * a16 + 2 * j;
            b_lds[buf][(nloc + 0) * BST + rk] = (int)(p & 0x0F0F0F0Fu);
            b_lds[buf][(nloc + 1) * BST + rk] = (int)((p >> 4) & 0x0F0F0F0Fu);
        }
    };

    LOADB(0, 0);
    LOADB(1, 1);
    WLDS(0, 0);
    asm volatile("s_waitcnt vmcnt(0) lgkmcnt(0)" ::: "memory");
    __builtin_amdgcn_s_barrier();
    asm volatile("" ::: "memory");

    #pragma unroll
    for (int c = 0; c < NCH; ++c) {
        const int cur = c & 1;
        const int gl  = c >> 1;
        if (c + 2 < NCH) LOADB(c + 2, cur);   // d[cur] flushed at iter c-1
        if ((c & 1) == 0) {   // group start: fetch Sx rows (L2-hot)
            sx0v = *reinterpret_cast<const int4*>(Sx + (g0 + gl) * 32 + kg * 4);
            sx1v = *reinterpret_cast<const int4*>(Sx + (g0 + gl) * 32 + 16 + kg * 4);
        }

        // B fragment: n-row (already nibble-extracted i8), dwords 4kg..4kg+3
        const int* bp = &b_lds[cur][(wid * 16 + cl) * BST + 4 * kg];
        int2 qa = *reinterpret_cast<const int2*>(bp);
        int2 qb = *reinterpret_cast<const int2*>(bp + 2);
        i32x4 bv; bv[0] = qa.x; bv[1] = qa.y; bv[2] = qb.x; bv[3] = qb.y;

        uint4 a0 = a_lds[(c * 2 + 0) * 64 + lane];
        uint4 a1 = a_lds[(c * 2 + 1) * 64 + lane];
        acc_i[0] = __builtin_amdgcn_mfma_i32_16x16x64_i8(
            __builtin_bit_cast(i32x4, a0), bv, acc_i[0], 0, 0, 0);
        acc_i[1] = __builtin_amdgcn_mfma_i32_16x16x64_i8(
            __builtin_bit_cast(i32x4, a1), bv, acc_i[1], 0, 0, 0);

        if (c & 1) {          // group end: integer zero-point fixup, scale
            const int   zz = zv[gl];
            const float ss = sv[gl];
            int sxa[8] = { sx0v.x, sx0v.y, sx0v.z, sx0v.w,
                           sx1v.x, sx1v.y, sx1v.z, sx1v.w };
            #pragma unroll
            for (int f = 0; f < 2; ++f)
                #pragma unroll
                for (int r = 0; r < 4; ++r) {
                    int tt = acc_i[f][r] - zz * sxa[f * 4 + r];
                    accf[f][r] = fmaf(ss, (float)tt, accf[f][r]);
                }
            acc_i[0] = i32x4{0, 0, 0, 0};
            acc_i[1] = i32x4{0, 0, 0, 0};
        }

        if (c + 1 < NCH) {
            WLDS(cur ^ 1, cur ^ 1);
            asm volatile("s_waitcnt lgkmcnt(0)" ::: "memory");
            __builtin_amdgcn_s_barrier();
            asm volatile("" ::: "memory");
        }
    }

    // epilogue: C/D layout col=lane&15, row=(lane>>4)*4+reg; out += delta_m*accf
    float4 dl0 = *reinterpret_cast<const float4*>(delta + kg * 4);
    float4 dl1 = *reinterpret_cast<const float4*>(delta + 16 + kg * 4);
    const float dla[8] = { dl0.x, dl0.y, dl0.z, dl0.w, dl1.x, dl1.y, dl1.z, dl1.w };
    #pragma unroll
    for (int f = 0; f < 2; ++f)
        #pragma unroll
        for (int r = 0; r < 4; ++r) {
            const int m = f * 16 + kg * 4 + r;
            unsafeAtomicAdd(out + (size_t)m * OUT_F + n, dla[f * 4 + r] * accf[f][r]);
        }
}

extern "C" void kernel_launch(void* const* d_in, const int* in_sizes, int n_in,
                              void* d_out, int out_size, void* d_ws, size_t ws_size,
                              hipStream_t stream)
{
    const float* inp    = (const float*)d_in[0];
    const int*   qw     = (const int*)d_in[1];
    const float* scales = (const float*)d_in[2];
    const int*   qz     = (const int*)d_in[3];
    const float* bias   = (const float*)d_in[4];
    float*       out    = (float*)d_out;

    uint4* xq    = (uint4*)d_ws;                          // 128 KB
    int*   Sx    = (int*)((char*)d_ws + 131072);          // 4 KB
    float* delta = (float*)((char*)d_ws + 131072 + 4096); // 128 B

    // blocks 0..31: quantize rows + Sx + delta; blocks 32..117: out = bias
    prep_kernel<<<118, 256, 0, stream>>>(inp, bias, xq, Sx, delta, out);

    // 1-D grid: kb = bid & 7 -> XCD id (dispatch round-robins blocks % 8)
    int4_gemm_i8<<<(OUT_F / BN) * KBS, 256, 0, stream>>>(
        xq, qw, scales, qz, Sx, delta, out);
}

// Round 16
// 28.455 us; speedup vs baseline: 1.5421x; 1.0404x over previous
//
#include <hip/hip_runtime.h>
#include <cstdint>

#define IN_F 4096
#define OUT_F 11008
#define Q_OUT 5504
#define GROUP 128
#define BATCH 32

#define KBS 8            // k-splits (gridDim.y)
#define GPB 4            // quant groups per block
#define NCH 8            // 64-k chunks per block (K=512)
#define BN 64            // output cols per block
#define BST 18           // b_lds dword stride per n-row: 16 data + 2 pad

typedef int   i32x4 __attribute__((ext_vector_type(4)));
typedef float f32x4 __attribute__((ext_vector_type(4)));

// ---------------------------------------------------------------------------
// Prep kernel, two roles by blockIdx:
//  blocks 0..31: row m: maxabs -> delta[m]; quantize x to i8 in MFMA A-frag
//    order; per-group row sums Sx[g][m] (i32, exact).
//  blocks 32..117: out[m][n] = bias[n]  (16 floats/thread; gemm atomics add)
// ---------------------------------------------------------------------------
__global__ __launch_bounds__(256)
void prep_kernel(const float* __restrict__ x,
                 const float* __restrict__ bias,
                 uint4* __restrict__ xq,     // 8192 slots of 16 i8
                 int*   __restrict__ Sx,     // [32 g][32 m]
                 float* __restrict__ delta,  // [32]
                 float* __restrict__ out)
{
    const int t = threadIdx.x;
    if (blockIdx.x >= 32) {
        const int base = (blockIdx.x - 32) * 4096 + t * 16;
        #pragma unroll
        for (int i = 0; i < 4; ++i)
            *reinterpret_cast<float4*>(out + base + i * 4) =
                *reinterpret_cast<const float4*>(bias + ((base + i * 4) % OUT_F));
        return;
    }
    const int m = blockIdx.x;
    const float* xr = x + (size_t)m * IN_F + t * 16;  // thread owns k=16t..16t+15
    float4 v[4];
    #pragma unroll
    for (int i = 0; i < 4; ++i) v[i] = reinterpret_cast<const float4*>(xr)[i];

    float lm = 0.f;
    #pragma unroll
    for (int i = 0; i < 4; ++i) {
        lm = fmaxf(lm, fmaxf(fmaxf(fabsf(v[i].x), fabsf(v[i].y)),
                             fmaxf(fabsf(v[i].z), fabsf(v[i].w))));
    }
    #pragma unroll
    for (int d = 32; d; d >>= 1) lm = fmaxf(lm, __shfl_xor(lm, d));
    __shared__ float wred[4];
    if ((t & 63) == 0) wred[t >> 6] = lm;
    __syncthreads();
    const float mx  = fmaxf(fmaxf(wred[0], wred[1]), fmaxf(wred[2], wred[3]));
    const float inv = mx > 0.f ? 127.0f / mx : 0.f;

    int q[16];
    #pragma unroll
    for (int i = 0; i < 4; ++i) {
        q[i * 4 + 0] = __float2int_rn(v[i].x * inv);
        q[i * 4 + 1] = __float2int_rn(v[i].y * inv);
        q[i * 4 + 2] = __float2int_rn(v[i].z * inv);
        q[i * 4 + 3] = __float2int_rn(v[i].w * inv);
    }
    uint4 w;
    uint* wp = reinterpret_cast<uint*>(&w);
    #pragma unroll
    for (int i = 0; i < 4; ++i)
        wp[i] = (q[i*4] & 255) | ((q[i*4+1] & 255) << 8) |
                ((q[i*4+2] & 255) << 16) | ((q[i*4+3] & 255) << 24);
    // slot = S*128 + f*64 + kg*16 + (m&15);  S=t>>2, kg=t&3, f=m>>4
    xq[(t >> 2) * 128 + (m >> 4) * 64 + (t & 3) * 16 + (m & 15)] = w;

    int psum = 0;
    #pragma unroll
    for (int i = 0; i < 16; ++i) psum += q[i];
    #pragma unroll
    for (int d = 4; d; d >>= 1) psum += __shfl_down(psum, d, 8);
    if ((t & 7) == 0) Sx[(t >> 3) * 32 + m] = psum;   // g = t>>3
    if (t == 0) delta[m] = mx * (1.0f / 127.0f);
}

// ---------------------------------------------------------------------------
// GEMM: per block M=32, N=64, K=512 (4 groups). 4 waves, each 16 cols.
// == r5 kernel verbatim (28.4 us, measured optimum over 11 structural
//    experiments: depth, burst length, barriers, hoisting, atomics, repack,
//    XCD placement all neutral-to-worse). Kernel time = one block's chain
//    (all blocks co-resident); service rate ~3.7 TB/s for this fragmented
//    read pattern is the empirical limit. ==
// A: i8 frags, 16 KB staged once via global_load_lds; 2 x ds_read_b128/chunk.
// B: nibbles unpacked to i8 bytes in LDS [64 n][16+2 dwords]; 2-deep register
//    prefetch; raw s_barrier + lgkmcnt(0) only in loop (B loads stay in
//    flight across barriers; vmcnt waits are compiler-counted, never 0).
// Per group (2 chunks): acc_i32 -> accf += s*(D - z*Sx).
// Epilogue: out += delta_m * accf via unsafeAtomicAdd (out = bias by prep).
// ---------------------------------------------------------------------------
__global__ __launch_bounds__(256, 4)
void int4_gemm_i8(const uint4* __restrict__ xq,
                  const int*   __restrict__ qw,
                  const float* __restrict__ scales,
                  const int*   __restrict__ qz,
                  const int*   __restrict__ Sx,
                  const float* __restrict__ delta,
                  float*       __restrict__ out)
{
    const int tid  = threadIdx.x;
    const int lane = tid & 63;
    const int wid  = tid >> 6;
    const int nb   = blockIdx.x;          // 0..171
    const int kb   = blockIdx.y;          // 0..7
    const int g0   = kb * GPB;
    const int k0b  = g0 * GROUP;

    __shared__ uint4 a_lds[1024];         // 16 KB, read-only after prologue
    __shared__ int   b_lds[2][64 * BST];  // 2 x 4.5 KB

    const int cl  = lane & 15;
    const int kg  = lane >> 4;
    const int n   = nb * BN + wid * 16 + cl;
    const int shn = (cl & 1) * 4;

    // ---- A stage: this kb's 1024 contiguous uint4 slots -> LDS, linear ----
    #pragma unroll
    for (int r = 0; r < 4; ++r) {
        const uint4* gp = xq + (size_t)kb * 1024 + r * 256 + tid;
        __builtin_amdgcn_global_load_lds(
            (const __attribute__((address_space(1))) uint32_t*)gp,
            (__attribute__((address_space(3))) uint32_t*)&a_lds[r * 256 + wid * 64],
            16, 0, 0);
    }

    // per-group constants
    int   zv[GPB];
    float sv[GPB];
    #pragma unroll
    for (int g = 0; g < GPB; ++g) {
        sv[g] = scales[(size_t)(g0 + g) * OUT_F + n];
        zv[g] = (qz[(size_t)(g0 + g) * Q_OUT + (n >> 1)] >> shn) & 15;
    }

    // B staging: thread (a16 = words 2a16,2a16+1; rk = rows 4rk..4rk+3)
    const int a16 = tid & 15;
    const int rk  = tid >> 4;

    uint2 d[2][4];                        // [set][row]
    i32x4 acc_i[2] = {};
    f32x4 accf[2]  = {};
    int4  sx0v = {}, sx1v = {};

    auto LOADB = [&](int c, int set) {
        const int kr = k0b + c * 64 + 4 * rk;
        #pragma unroll
        for (int i = 0; i < 4; ++i)
            d[set][i] = *reinterpret_cast<const uint2*>(
                qw + (size_t)(kr + i) * Q_OUT + nb * 32 + 2 * a16);
    };
    auto WLDS = [&](int buf, int set) {
        #pragma unroll
        for (int j = 0; j < 2; ++j) {
            // k-major dword: low bytes of 4 consecutive k-rows, word 2a16+j
            uint b0 = (j ? d[set][0].y : d[set][0].x) & 255u;
            uint b1 = (j ? d[set][1].y : d[set][1].x) & 255u;
            uint b2 = (j ? d[set][2].y : d[set][2].x) & 255u;
            uint b3 = (j ? d[set][3].y : d[set][3].x) & 255u;
            uint p  = b0 | (b1 << 8) | (b2 << 16) | (b3 << 24);
            const int nloc = 4 * a16 + 2 * j;
            b_lds[buf][(nloc + 0) * BST + rk] = (int)(p & 0x0F0F0F0Fu);
            b_lds[buf][(nloc + 1) * BST + rk] = (int)((p >> 4) & 0x0F0F0F0Fu);
        }
    };

    LOADB(0, 0);
    LOADB(1, 1);
    WLDS(0, 0);
    asm volatile("s_waitcnt vmcnt(0) lgkmcnt(0)" ::: "memory");
    __builtin_amdgcn_s_barrier();
    asm volatile("" ::: "memory");

    #pragma unroll
    for (int c = 0; c < NCH; ++c) {
        const int cur = c & 1;
        const int gl  = c >> 1;
        if (c + 2 < NCH) LOADB(c + 2, cur);   // d[cur] flushed at iter c-1
        if ((c & 1) == 0) {   // group start: fetch Sx rows (L2-hot)
            sx0v = *reinterpret_cast<const int4*>(Sx + (g0 + gl) * 32 + kg * 4);
            sx1v = *reinterpret_cast<const int4*>(Sx + (g0 + gl) * 32 + 16 + kg * 4);
        }

        // B fragment: n-row (already nibble-extracted i8), dwords 4kg..4kg+3
        const int* bp = &b_lds[cur][(wid * 16 + cl) * BST + 4 * kg];
        int2 qa = *reinterpret_cast<const int2*>(bp);
        int2 qb = *reinterpret_cast<const int2*>(bp + 2);
        i32x4 bv; bv[0] = qa.x; bv[1] = qa.y; bv[2] = qb.x; bv[3] = qb.y;

        uint4 a0 = a_lds[(c * 2 + 0) * 64 + lane];
        uint4 a1 = a_lds[(c * 2 + 1) * 64 + lane];
        acc_i[0] = __builtin_amdgcn_mfma_i32_16x16x64_i8(
            __builtin_bit_cast(i32x4, a0), bv, acc_i[0], 0, 0, 0);
        acc_i[1] = __builtin_amdgcn_mfma_i32_16x16x64_i8(
            __builtin_bit_cast(i32x4, a1), bv, acc_i[1], 0, 0, 0);

        if (c & 1) {          // group end: integer zero-point fixup, scale
            const int   zz = zv[gl];
            const float ss = sv[gl];
            int sxa[8] = { sx0v.x, sx0v.y, sx0v.z, sx0v.w,
                           sx1v.x, sx1v.y, sx1v.z, sx1v.w };
            #pragma unroll
            for (int f = 0; f < 2; ++f)
                #pragma unroll
                for (int r = 0; r < 4; ++r) {
                    int tt = acc_i[f][r] - zz * sxa[f * 4 + r];
                    accf[f][r] = fmaf(ss, (float)tt, accf[f][r]);
                }
            acc_i[0] = i32x4{0, 0, 0, 0};
            acc_i[1] = i32x4{0, 0, 0, 0};
        }

        if (c + 1 < NCH) {
            WLDS(cur ^ 1, cur ^ 1);
            asm volatile("s_waitcnt lgkmcnt(0)" ::: "memory");
            __builtin_amdgcn_s_barrier();
            asm volatile("" ::: "memory");
        }
    }

    // epilogue: C/D layout col=lane&15, row=(lane>>4)*4+reg; out += delta_m*accf
    float4 dl0 = *reinterpret_cast<const float4*>(delta + kg * 4);
    float4 dl1 = *reinterpret_cast<const float4*>(delta + 16 + kg * 4);
    const float dla[8] = { dl0.x, dl0.y, dl0.z, dl0.w, dl1.x, dl1.y, dl1.z, dl1.w };
    #pragma unroll
    for (int f = 0; f < 2; ++f)
        #pragma unroll
        for (int r = 0; r < 4; ++r) {
            const int m = f * 16 + kg * 4 + r;
            unsafeAtomicAdd(out + (size_t)m * OUT_F + n, dla[f * 4 + r] * accf[f][r]);
        }
}

extern "C" void kernel_launch(void* const* d_in, const int* in_sizes, int n_in,
                              void* d_out, int out_size, void* d_ws, size_t ws_size,
                              hipStream_t stream)
{
    const float* inp    = (const float*)d_in[0];
    const int*   qw     = (const int*)d_in[1];
    const float* scales = (const float*)d_in[2];
    const int*   qz     = (const int*)d_in[3];
    const float* bias   = (const float*)d_in[4];
    float*       out    = (float*)d_out;

    uint4* xq    = (uint4*)d_ws;                          // 128 KB
    int*   Sx    = (int*)((char*)d_ws + 131072);          // 4 KB
    float* delta = (float*)((char*)d_ws + 131072 + 4096); // 128 B

    // blocks 0..31: quantize rows + Sx + delta; blocks 32..117: out = bias
    prep_kernel<<<118, 256, 0, stream>>>(inp, bias, xq, Sx, delta, out);

    int4_gemm_i8<<<dim3(OUT_F / BN, KBS), 256, 0, stream>>>(
        xq, qw, scales, qz, Sx, delta, out);
}